// Round 4
// baseline (190.712 us; speedup 1.0000x reference)
//
#include <hip/hip_runtime.h>
#include <math.h>

#define BB 8192
#define DD 768
#define EE 16
#define PP 4
#define RPB 4   // rows per block; grid = 2048 blocks

typedef float f32x4 __attribute__((ext_vector_type(4)));

__global__ __launch_bounds__(256) void moe_fused(
    const float* __restrict__ h,      // [B, D, E]
    const float* __restrict__ x,      // [B, D]
    const float* __restrict__ W,      // [E, D]
    const float* __restrict__ bias,   // [E]
    const float* __restrict__ Pw,     // [P, E, E]
    float* __restrict__ y,            // [B, D]
    float* __restrict__ avgs)         // [32]: soft[16] ++ hard[16]
{
    __shared__ float Pm[EE * EE];
    __shared__ float sp_lds[RPB][EE];
    __shared__ float aS[EE], aH[EE];

    const int t    = threadIdx.x;
    const int w    = t >> 6;        // wave id == row within block (phase A)
    const int lane = t & 63;
    const int e    = lane & 15;     // expert
    const int seg  = lane >> 4;     // k-segment 0..3
    const int row  = blockIdx.x * RPB + w;

    // ---- P_mean -> LDS ----
    {
        float s = 0.f;
        #pragma unroll
        for (int p = 0; p < PP; ++p) s += Pw[p * EE * EE + t];
        Pm[t] = s * 0.25f;
    }
    if (t < EE) { aS[t] = 0.f; aH[t] = 0.f; }
    __syncthreads();

    // ---- Phase A: router logit for (row, e) ----
    const f32x4* x4 = (const f32x4*)(x + (size_t)row * DD);
    const f32x4* w4 = (const f32x4*)(W + (size_t)e * DD);
    f32x4 acc = {0.f, 0.f, 0.f, 0.f};
    #pragma unroll 6
    for (int i = 0; i < 48; ++i) {
        const int k4 = seg + 4 * i;
        f32x4 a = x4[k4], b = w4[k4];
        acc.x = fmaf(a.x, b.x, acc.x);
        acc.y = fmaf(a.y, b.y, acc.y);
        acc.z = fmaf(a.z, b.z, acc.z);
        acc.w = fmaf(a.w, b.w, acc.w);
    }
    float part = (acc.x + acc.y) + (acc.z + acc.w);
    part += __shfl_xor(part, 16, 64);
    part += __shfl_xor(part, 32, 64);
    const float logit = part + bias[e];

    // top-1 across 16 experts
    float v0 = logit; int i0 = e;
    #pragma unroll
    for (int m = 1; m < 16; m <<= 1) {
        float ov = __shfl_xor(v0, m, 16);
        int   oi = __shfl_xor(i0, m, 16);
        if (ov > v0 || (ov == v0 && oi < i0)) { v0 = ov; i0 = oi; }
    }
    // top-2
    float v1 = (e == i0) ? -INFINITY : logit; int i1 = e;
    #pragma unroll
    for (int m = 1; m < 16; m <<= 1) {
        float ov = __shfl_xor(v1, m, 16);
        int   oi = __shfl_xor(i1, m, 16);
        if (ov > v1 || (ov == v1 && oi < i1)) { v1 = ov; i1 = oi; }
    }

    // reference quirk: scattered==0.0 -> -inf before softmax
    const float z0 = (v0 == 0.f) ? -INFINITY : v0;
    const float z1 = (v1 == 0.f) ? -INFINITY : v1;
    const float mx = fmaxf(z0, z1);
    const float e0 = expf(z0 - mx), e1 = expf(z1 - mx);
    const float inv = 1.f / (e0 + e1);
    const float sm0 = e0 * inv, sm1 = e1 * inv;

    const float s = sm0 * Pm[i0 * EE + e] + sm1 * Pm[i1 * EE + e];
    if (seg == 0) {
        sp_lds[w][e] = s;
        atomicAdd(&aS[e], s);
        atomicAdd(&aH[e], (s >= 1e-5f) ? 1.f : 0.f);
    }
    __syncthreads();

    if (t < EE) {
        const float invB = 1.0f / (float)BB;
        atomicAdd(&avgs[t],      aS[t] * invB);
        atomicAdd(&avgs[EE + t], aH[t] * invB);
    }

    // ---- Phase B: stream h with nontemporal loads, 12 loads in flight ----
    // Each thread owns 3 output elements per row: d = t, t+256, t+512.
    for (int r = 0; r < RPB; ++r) {
        // sp row -> registers (LDS broadcast)
        const f32x4 s0 = ((const f32x4*)&sp_lds[r][0])[0];
        const f32x4 s1 = ((const f32x4*)&sp_lds[r][0])[1];
        const f32x4 s2 = ((const f32x4*)&sp_lds[r][0])[2];
        const f32x4 s3 = ((const f32x4*)&sp_lds[r][0])[3];

        const size_t rw = (size_t)(blockIdx.x * RPB + r);
        const f32x4* h4 = (const f32x4*)(h + rw * DD * EE);
        float* yr = y + rw * DD;

        // issue all 12 independent loads first (streaming, no L2/L3 allocate)
        f32x4 L[12];
        #pragma unroll
        for (int j = 0; j < 3; ++j) {
            const int d = t + j * 256;
            L[j * 4 + 0] = __builtin_nontemporal_load(h4 + 4 * d + 0);
            L[j * 4 + 1] = __builtin_nontemporal_load(h4 + 4 * d + 1);
            L[j * 4 + 2] = __builtin_nontemporal_load(h4 + 4 * d + 2);
            L[j * 4 + 3] = __builtin_nontemporal_load(h4 + 4 * d + 3);
        }
        #pragma unroll
        for (int j = 0; j < 3; ++j) {
            const f32x4 a = L[j * 4 + 0], b = L[j * 4 + 1];
            const f32x4 c = L[j * 4 + 2], dq = L[j * 4 + 3];
            float p = a.x * s0.x;
            p = fmaf(a.y,  s0.y, p); p = fmaf(a.z,  s0.z, p); p = fmaf(a.w,  s0.w, p);
            p = fmaf(b.x,  s1.x, p); p = fmaf(b.y,  s1.y, p); p = fmaf(b.z,  s1.z, p); p = fmaf(b.w,  s1.w, p);
            p = fmaf(c.x,  s2.x, p); p = fmaf(c.y,  s2.y, p); p = fmaf(c.z,  s2.z, p); p = fmaf(c.w,  s2.w, p);
            p = fmaf(dq.x, s3.x, p); p = fmaf(dq.y, s3.y, p); p = fmaf(dq.z, s3.z, p); p = fmaf(dq.w, s3.w, p);
            __builtin_nontemporal_store(p, yr + t + j * 256);
        }
    }
}

extern "C" void kernel_launch(void* const* d_in, const int* in_sizes, int n_in,
                              void* d_out, int out_size, void* d_ws, size_t ws_size,
                              hipStream_t stream) {
    const float* h    = (const float*)d_in[0];   // [8192, 768, 16]
    const float* x    = (const float*)d_in[1];   // [8192, 768]
    const float* W    = (const float*)d_in[2];   // [16, 768]
    const float* bias = (const float*)d_in[3];   // [16]
    const float* Pw   = (const float*)d_in[4];   // [4, 16, 16]

    float* y    = (float*)d_out;                 // [8192, 768]
    float* avgs = y + (size_t)BB * DD;           // soft[16] ++ hard[16]

    hipMemsetAsync(avgs, 0, 2 * EE * sizeof(float), stream);

    moe_fused<<<BB / RPB, 256, 0, stream>>>(h, x, W, bias, Pw, y, avgs);
}

// Round 5
// 157.982 us; speedup vs baseline: 1.2072x; 1.2072x over previous
//
#include <hip/hip_runtime.h>
#include <math.h>

#define BB 8192
#define DD 768
#define EE 16
#define PP 4

typedef float f32x4 __attribute__((ext_vector_type(4)));

// ---------------- K_gate: router + top2 + softmax + permute + averages ----------
// 2048 blocks x 256 threads; one wave per row -> all 8192 rows in flight at once.
__global__ __launch_bounds__(256) void gate_kernel(
    const float* __restrict__ x,     // [B, D]
    const float* __restrict__ W,     // [E, D]
    const float* __restrict__ bias,  // [E]
    const float* __restrict__ Pw,    // [P, E, E]
    float* __restrict__ sp_ws,       // [B, E]
    float* __restrict__ avgs)        // [32]
{
    __shared__ float Pm[EE * EE];
    __shared__ float aS[EE], aH[EE];

    const int t    = threadIdx.x;
    const int w    = t >> 6;
    const int lane = t & 63;
    const int e    = lane & 15;
    const int seg  = lane >> 4;
    const int row  = blockIdx.x * 4 + w;

    {
        float s = 0.f;
        #pragma unroll
        for (int p = 0; p < PP; ++p) s += Pw[p * EE * EE + t];
        Pm[t] = s * 0.25f;
    }
    if (t < EE) { aS[t] = 0.f; aH[t] = 0.f; }
    __syncthreads();

    const f32x4* x4 = (const f32x4*)(x + (size_t)row * DD);
    const f32x4* w4 = (const f32x4*)(W + (size_t)e * DD);
    f32x4 acc = {0.f, 0.f, 0.f, 0.f};
    #pragma unroll 6
    for (int i = 0; i < 48; ++i) {
        const int k4 = seg + 4 * i;
        f32x4 a = x4[k4], b = w4[k4];
        acc.x = fmaf(a.x, b.x, acc.x);
        acc.y = fmaf(a.y, b.y, acc.y);
        acc.z = fmaf(a.z, b.z, acc.z);
        acc.w = fmaf(a.w, b.w, acc.w);
    }
    float part = (acc.x + acc.y) + (acc.z + acc.w);
    part += __shfl_xor(part, 16, 64);
    part += __shfl_xor(part, 32, 64);
    const float logit = part + bias[e];

    // top-1 across 16 experts
    float v0 = logit; int i0 = e;
    #pragma unroll
    for (int m = 1; m < 16; m <<= 1) {
        float ov = __shfl_xor(v0, m, 16);
        int   oi = __shfl_xor(i0, m, 16);
        if (ov > v0 || (ov == v0 && oi < i0)) { v0 = ov; i0 = oi; }
    }
    // top-2
    float v1 = (e == i0) ? -INFINITY : logit; int i1 = e;
    #pragma unroll
    for (int m = 1; m < 16; m <<= 1) {
        float ov = __shfl_xor(v1, m, 16);
        int   oi = __shfl_xor(i1, m, 16);
        if (ov > v1 || (ov == v1 && oi < i1)) { v1 = ov; i1 = oi; }
    }

    // reference quirk: scattered==0.0 -> -inf before softmax
    const float z0 = (v0 == 0.f) ? -INFINITY : v0;
    const float z1 = (v1 == 0.f) ? -INFINITY : v1;
    const float mx = fmaxf(z0, z1);
    const float e0 = expf(z0 - mx), e1 = expf(z1 - mx);
    const float inv = 1.f / (e0 + e1);
    const float sm0 = e0 * inv, sm1 = e1 * inv;

    const float s = sm0 * Pm[i0 * EE + e] + sm1 * Pm[i1 * EE + e];
    if (seg == 0) {
        sp_ws[(size_t)row * EE + e] = s;
        atomicAdd(&aS[e], s);
        atomicAdd(&aH[e], (s >= 1e-5f) ? 1.f : 0.f);
    }
    __syncthreads();

    if (t < EE) {
        const float invB = 1.0f / (float)BB;
        atomicAdd(&avgs[t],      aS[t] * invB);
        atomicAdd(&avgs[EE + t], aH[t] * invB);
    }
}

// ---------------- K_stream: minimal pure streamer --------------------------------
// 2048 blocks x 256 threads, 4 rows/block. No LDS, no shuffles, no atomics.
__global__ __launch_bounds__(256, 4) void stream_kernel(
    const float* __restrict__ h,      // [B, D, E]
    const float* __restrict__ sp_ws,  // [B, E]
    float* __restrict__ y)            // [B, D]
{
    const int t = threadIdx.x;

    #pragma unroll 1
    for (int rr = 0; rr < 4; ++rr) {
        const size_t row = (size_t)blockIdx.x * 4 + rr;

        // sp row -> registers (64B row, L2-hot; every lane reads its quad)
        const f32x4* sp4 = (const f32x4*)(sp_ws + row * EE);
        const f32x4 s0 = sp4[0], s1 = sp4[1], s2 = sp4[2], s3 = sp4[3];

        const f32x4* h4 = (const f32x4*)(h + row * DD * EE);
        float* yr = y + row * DD;

        // 12 independent dwordx4 loads in flight per lane
        f32x4 L[12];
        #pragma unroll
        for (int j = 0; j < 3; ++j) {
            const int d = t + j * 256;
            L[j * 4 + 0] = h4[4 * d + 0];
            L[j * 4 + 1] = h4[4 * d + 1];
            L[j * 4 + 2] = h4[4 * d + 2];
            L[j * 4 + 3] = h4[4 * d + 3];
        }
        #pragma unroll
        for (int j = 0; j < 3; ++j) {
            const f32x4 a = L[j * 4 + 0], b = L[j * 4 + 1];
            const f32x4 c = L[j * 4 + 2], dq = L[j * 4 + 3];
            float p = a.x * s0.x;
            p = fmaf(a.y,  s0.y, p); p = fmaf(a.z,  s0.z, p); p = fmaf(a.w,  s0.w, p);
            p = fmaf(b.x,  s1.x, p); p = fmaf(b.y,  s1.y, p); p = fmaf(b.z,  s1.z, p); p = fmaf(b.w,  s1.w, p);
            p = fmaf(c.x,  s2.x, p); p = fmaf(c.y,  s2.y, p); p = fmaf(c.z,  s2.z, p); p = fmaf(c.w,  s2.w, p);
            p = fmaf(dq.x, s3.x, p); p = fmaf(dq.y, s3.y, p); p = fmaf(dq.z, s3.z, p); p = fmaf(dq.w, s3.w, p);
            yr[t + j * 256] = p;
        }
    }
}

extern "C" void kernel_launch(void* const* d_in, const int* in_sizes, int n_in,
                              void* d_out, int out_size, void* d_ws, size_t ws_size,
                              hipStream_t stream) {
    const float* h    = (const float*)d_in[0];   // [8192, 768, 16]
    const float* x    = (const float*)d_in[1];   // [8192, 768]
    const float* W    = (const float*)d_in[2];   // [16, 768]
    const float* bias = (const float*)d_in[3];   // [16]
    const float* Pw   = (const float*)d_in[4];   // [4, 16, 16]

    float* y     = (float*)d_out;                // [8192, 768]
    float* avgs  = y + (size_t)BB * DD;          // soft[16] ++ hard[16]
    float* sp_ws = (float*)d_ws;                 // [8192, 16] = 512 KB

    hipMemsetAsync(avgs, 0, 2 * EE * sizeof(float), stream);

    gate_kernel<<<BB / 4, 256, 0, stream>>>(x, W, bias, Pw, sp_ws, avgs);
    stream_kernel<<<BB / 4, 256, 0, stream>>>(h, sp_ws, y);
}

// Round 6
// 139.381 us; speedup vs baseline: 1.3683x; 1.1335x over previous
//
#include <hip/hip_runtime.h>
#include <math.h>

#define BB 8192
#define DD 768
#define EE 16
#define PP 4
#define RPB 4               // rows per block
#define NBLK (BB / RPB)     // 2048 blocks

typedef float f32x4 __attribute__((ext_vector_type(4)));

// ---- K1: fused gate + stream. Writes y and per-block partial avg sums (no atomics).
__global__ __launch_bounds__(256) void moe_fused(
    const float* __restrict__ h,      // [B, D, E]
    const float* __restrict__ x,      // [B, D]
    const float* __restrict__ W,      // [E, D]
    const float* __restrict__ bias,   // [E]
    const float* __restrict__ Pw,     // [P, E, E]
    float* __restrict__ y,            // [B, D]
    float* __restrict__ partials)     // [NBLK][32]: soft[16] ++ hard[16]
{
    __shared__ float Pm[EE * EE];
    __shared__ float sp_lds[RPB][EE];

    const int t    = threadIdx.x;
    const int w    = t >> 6;        // wave id == row within block (phase A)
    const int lane = t & 63;
    const int e    = lane & 15;     // expert
    const int seg  = lane >> 4;     // k-segment 0..3
    const int row  = blockIdx.x * RPB + w;

    // ---- P_mean -> LDS ----
    {
        float s = 0.f;
        #pragma unroll
        for (int p = 0; p < PP; ++p) s += Pw[p * EE * EE + t];
        Pm[t] = s * 0.25f;
    }
    __syncthreads();

    // ---- Phase A: router logit for (row, e); each lane dots 192 elems ----
    const f32x4* x4 = (const f32x4*)(x + (size_t)row * DD);
    const f32x4* w4 = (const f32x4*)(W + (size_t)e * DD);
    f32x4 acc = {0.f, 0.f, 0.f, 0.f};
    #pragma unroll 6
    for (int i = 0; i < 48; ++i) {
        const int k4 = seg + 4 * i;
        f32x4 a = x4[k4], b = w4[k4];
        acc.x = fmaf(a.x, b.x, acc.x);
        acc.y = fmaf(a.y, b.y, acc.y);
        acc.z = fmaf(a.z, b.z, acc.z);
        acc.w = fmaf(a.w, b.w, acc.w);
    }
    float part = (acc.x + acc.y) + (acc.z + acc.w);
    part += __shfl_xor(part, 16, 64);
    part += __shfl_xor(part, 32, 64);
    const float logit = part + bias[e];

    // top-1 across 16 experts
    float v0 = logit; int i0 = e;
    #pragma unroll
    for (int m = 1; m < 16; m <<= 1) {
        float ov = __shfl_xor(v0, m, 16);
        int   oi = __shfl_xor(i0, m, 16);
        if (ov > v0 || (ov == v0 && oi < i0)) { v0 = ov; i0 = oi; }
    }
    // top-2
    float v1 = (e == i0) ? -INFINITY : logit; int i1 = e;
    #pragma unroll
    for (int m = 1; m < 16; m <<= 1) {
        float ov = __shfl_xor(v1, m, 16);
        int   oi = __shfl_xor(i1, m, 16);
        if (ov > v1 || (ov == v1 && oi < i1)) { v1 = ov; i1 = oi; }
    }

    // reference quirk: scattered==0.0 -> -inf before softmax
    const float z0 = (v0 == 0.f) ? -INFINITY : v0;
    const float z1 = (v1 == 0.f) ? -INFINITY : v1;
    const float mx = fmaxf(z0, z1);
    const float e0 = expf(z0 - mx), e1 = expf(z1 - mx);
    const float inv = 1.f / (e0 + e1);
    const float sm0 = e0 * inv, sm1 = e1 * inv;

    const float s = sm0 * Pm[i0 * EE + e] + sm1 * Pm[i1 * EE + e];
    if (seg == 0) sp_lds[w][e] = s;
    __syncthreads();

    // ---- per-block partial averages (replaces global atomics + memset) ----
    if (t < EE) {
        partials[(size_t)blockIdx.x * 32 + t] =
            sp_lds[0][t] + sp_lds[1][t] + sp_lds[2][t] + sp_lds[3][t];
    } else if (t < 2 * EE) {
        const int c = t - EE;
        float hs = 0.f;
        #pragma unroll
        for (int r = 0; r < RPB; ++r) hs += (sp_lds[r][c] >= 1e-5f) ? 1.f : 0.f;
        partials[(size_t)blockIdx.x * 32 + t] = hs;
    }

    // ---- Phase B: stream h (identical to round-3 winner) ----
    const int q = t & 3;   // which expert-quad this lane owns
    for (int r = 0; r < RPB; ++r) {
        const f32x4 s4 = ((const f32x4*)&sp_lds[r][0])[q];
        const size_t rw = (size_t)(blockIdx.x * RPB + r);
        const f32x4* h4 = (const f32x4*)(h + rw * DD * EE);
        float* yr = y + rw * DD;
        #pragma unroll
        for (int it = 0; it < 12; ++it) {
            const int u = it * 256 + t;       // wave reads 1KB contiguous/instr
            f32x4 a = h4[u];
            float p = a.x * s4.x + a.y * s4.y + a.z * s4.z + a.w * s4.w;
            p += __shfl_xor(p, 1, 64);        // quad reduce
            p += __shfl_xor(p, 2, 64);
            if (q == 0) yr[u >> 2] = p;
        }
    }
}

// ---- K2: single-block reduction of partials -> avgs (32 floats). ----
__global__ __launch_bounds__(256) void avg_reduce(
    const float* __restrict__ partials,   // [NBLK][32]
    float* __restrict__ avgs)             // [32]
{
    __shared__ float red[8][32];
    const int t = threadIdx.x;
    const int col   = t & 31;
    const int chunk = t >> 5;             // 0..7, each sums 256 block-rows
    float s = 0.f;
    const int base = chunk * (NBLK / 8);
    for (int i = 0; i < NBLK / 8; ++i)
        s += partials[(size_t)(base + i) * 32 + col];
    red[chunk][col] = s;
    __syncthreads();
    if (t < 32) {
        float tot = 0.f;
        #pragma unroll
        for (int c = 0; c < 8; ++c) tot += red[c][t];
        avgs[t] = tot * (1.0f / (float)BB);
    }
}

extern "C" void kernel_launch(void* const* d_in, const int* in_sizes, int n_in,
                              void* d_out, int out_size, void* d_ws, size_t ws_size,
                              hipStream_t stream) {
    const float* h    = (const float*)d_in[0];   // [8192, 768, 16]
    const float* x    = (const float*)d_in[1];   // [8192, 768]
    const float* W    = (const float*)d_in[2];   // [16, 768]
    const float* bias = (const float*)d_in[3];   // [16]
    const float* Pw   = (const float*)d_in[4];   // [4, 16, 16]

    float* y        = (float*)d_out;             // [8192, 768]
    float* avgs     = y + (size_t)BB * DD;       // soft[16] ++ hard[16]
    float* partials = (float*)d_ws;              // [2048][32] = 256 KB

    moe_fused<<<NBLK, 256, 0, stream>>>(h, x, W, bias, Pw, y, partials);
    avg_reduce<<<1, 256, 0, stream>>>(partials, avgs);
}

// Round 7
// 132.539 us; speedup vs baseline: 1.4389x; 1.0516x over previous
//
#include <hip/hip_runtime.h>
#include <math.h>

#define BB 8192
#define DD 768
#define EE 16
#define PP 4
#define RPB 4               // rows per block
#define NBLK (BB / RPB)     // 2048 blocks

typedef float f32x4 __attribute__((ext_vector_type(4)));

// ---- K1: fused gate + stream. Writes y and transposed per-block partials.
__global__ __launch_bounds__(256, 4) void moe_fused(
    const float* __restrict__ h,      // [B, D, E]
    const float* __restrict__ x,      // [B, D]
    const float* __restrict__ W,      // [E, D]
    const float* __restrict__ bias,   // [E]
    const float* __restrict__ Pw,     // [P, E, E]
    float* __restrict__ y,            // [B, D]
    float* __restrict__ partials)     // [32][NBLK] transposed: soft rows 0..15, hard 16..31
{
    __shared__ float Pm[EE * EE];
    __shared__ float sp_lds[RPB][EE];

    const int t    = threadIdx.x;
    const int w    = t >> 6;        // wave id == row within block (phase A)
    const int lane = t & 63;
    const int e    = lane & 15;     // expert
    const int seg  = lane >> 4;     // k-segment 0..3
    const int row  = blockIdx.x * RPB + w;

    // ---- P_mean -> LDS ----
    {
        float s = 0.f;
        #pragma unroll
        for (int p = 0; p < PP; ++p) s += Pw[p * EE * EE + t];
        Pm[t] = s * 0.25f;
    }
    __syncthreads();

    // ---- Phase A: router logit for (row, e); each lane dots 192 elems ----
    const f32x4* x4 = (const f32x4*)(x + (size_t)row * DD);
    const f32x4* w4 = (const f32x4*)(W + (size_t)e * DD);
    f32x4 acc = {0.f, 0.f, 0.f, 0.f};
    #pragma unroll 6
    for (int i = 0; i < 48; ++i) {
        const int k4 = seg + 4 * i;
        f32x4 a = x4[k4], b = w4[k4];
        acc.x = fmaf(a.x, b.x, acc.x);
        acc.y = fmaf(a.y, b.y, acc.y);
        acc.z = fmaf(a.z, b.z, acc.z);
        acc.w = fmaf(a.w, b.w, acc.w);
    }
    float part = (acc.x + acc.y) + (acc.z + acc.w);
    part += __shfl_xor(part, 16, 64);
    part += __shfl_xor(part, 32, 64);
    const float logit = part + bias[e];

    // top-1 across 16 experts
    float v0 = logit; int i0 = e;
    #pragma unroll
    for (int m = 1; m < 16; m <<= 1) {
        float ov = __shfl_xor(v0, m, 16);
        int   oi = __shfl_xor(i0, m, 16);
        if (ov > v0 || (ov == v0 && oi < i0)) { v0 = ov; i0 = oi; }
    }
    // top-2
    float v1 = (e == i0) ? -INFINITY : logit; int i1 = e;
    #pragma unroll
    for (int m = 1; m < 16; m <<= 1) {
        float ov = __shfl_xor(v1, m, 16);
        int   oi = __shfl_xor(i1, m, 16);
        if (ov > v1 || (ov == v1 && oi < i1)) { v1 = ov; i1 = oi; }
    }

    // reference quirk: scattered==0.0 -> -inf before softmax
    const float z0 = (v0 == 0.f) ? -INFINITY : v0;
    const float z1 = (v1 == 0.f) ? -INFINITY : v1;
    const float mx = fmaxf(z0, z1);
    const float e0 = expf(z0 - mx), e1 = expf(z1 - mx);
    const float inv = 1.f / (e0 + e1);
    const float sm0 = e0 * inv, sm1 = e1 * inv;

    const float s = sm0 * Pm[i0 * EE + e] + sm1 * Pm[i1 * EE + e];
    if (seg == 0) sp_lds[w][e] = s;
    __syncthreads();

    // ---- per-block partials, transposed layout [32][NBLK] ----
    if (t < EE) {
        partials[(size_t)t * NBLK + blockIdx.x] =
            sp_lds[0][t] + sp_lds[1][t] + sp_lds[2][t] + sp_lds[3][t];
    } else if (t < 2 * EE) {
        const int c = t - EE;
        float hs = 0.f;
        #pragma unroll
        for (int r = 0; r < RPB; ++r) hs += (sp_lds[r][c] >= 1e-5f) ? 1.f : 0.f;
        partials[(size_t)t * NBLK + blockIdx.x] = hs;
    }

    // ---- Phase B: stream h (R3 winner pattern) ----
    const int q = t & 3;   // which expert-quad this lane owns
    for (int r = 0; r < RPB; ++r) {
        const f32x4 s4 = ((const f32x4*)&sp_lds[r][0])[q];
        const size_t rw = (size_t)(blockIdx.x * RPB + r);
        const f32x4* h4 = (const f32x4*)(h + rw * DD * EE);
        float* yr = y + rw * DD;
        #pragma unroll
        for (int it = 0; it < 12; ++it) {
            const int u = it * 256 + t;       // wave reads 1KB contiguous/instr
            f32x4 a = h4[u];
            float p = a.x * s4.x + a.y * s4.y + a.z * s4.z + a.w * s4.w;
            p += __shfl_xor(p, 1, 64);        // quad reduce
            p += __shfl_xor(p, 2, 64);
            if (q == 0) yr[u >> 2] = p;
        }
    }
}

// ---- K2: 32 blocks; block b streams its contiguous 8 KB row of partials. ----
__global__ __launch_bounds__(256) void avg_reduce(
    const float* __restrict__ partials,   // [32][NBLK]
    float* __restrict__ avgs)             // [32]
{
    __shared__ float red[4];
    const int t = threadIdx.x;
    const int b = blockIdx.x;
    const float* rowp = partials + (size_t)b * NBLK;

    float s = 0.f;
    #pragma unroll
    for (int k = 0; k < NBLK / 256; ++k)   // 8 coalesced passes
        s += rowp[t + k * 256];
    // wave reduce
    #pragma unroll
    for (int off = 32; off >= 1; off >>= 1)
        s += __shfl_xor(s, off, 64);
    if ((t & 63) == 0) red[t >> 6] = s;
    __syncthreads();
    if (t == 0)
        avgs[b] = (red[0] + red[1] + red[2] + red[3]) * (1.0f / (float)BB);
}

extern "C" void kernel_launch(void* const* d_in, const int* in_sizes, int n_in,
                              void* d_out, int out_size, void* d_ws, size_t ws_size,
                              hipStream_t stream) {
    const float* h    = (const float*)d_in[0];   // [8192, 768, 16]
    const float* x    = (const float*)d_in[1];   // [8192, 768]
    const float* W    = (const float*)d_in[2];   // [16, 768]
    const float* bias = (const float*)d_in[3];   // [16]
    const float* Pw   = (const float*)d_in[4];   // [4, 16, 16]

    float* y        = (float*)d_out;             // [8192, 768]
    float* avgs     = y + (size_t)BB * DD;       // soft[16] ++ hard[16]
    float* partials = (float*)d_ws;              // [32][2048] = 256 KB

    moe_fused<<<NBLK, 256, 0, stream>>>(h, x, W, bias, Pw, y, partials);
    avg_reduce<<<32, 256, 0, stream>>>(partials, avgs);
}

// Round 8
// 130.474 us; speedup vs baseline: 1.4617x; 1.0158x over previous
//
#include <hip/hip_runtime.h>
#include <math.h>

#define BB 8192
#define DD 768
#define EE 16
#define PP 4
#define RPB 4               // rows per block
#define NBLK (BB / RPB)     // 2048 blocks

typedef float f32x4 __attribute__((ext_vector_type(4)));

// ---- K1: fused gate + stream. NT stores for y; partials written after stream.
__global__ __launch_bounds__(256, 4) void moe_fused(
    const float* __restrict__ h,      // [B, D, E]
    const float* __restrict__ x,      // [B, D]
    const float* __restrict__ W,      // [E, D]
    const float* __restrict__ bias,   // [E]
    const float* __restrict__ Pw,     // [P, E, E]
    float* __restrict__ y,            // [B, D]
    float* __restrict__ partials)     // [32][NBLK] transposed: soft 0..15, hard 16..31
{
    __shared__ float Pm[EE * EE];
    __shared__ float sp_lds[RPB][EE];

    const int t    = threadIdx.x;
    const int w    = t >> 6;        // wave id == row within block (phase A)
    const int lane = t & 63;
    const int e    = lane & 15;     // expert
    const int seg  = lane >> 4;     // k-segment 0..3
    const int row  = blockIdx.x * RPB + w;

    // ---- P_mean -> LDS ----
    {
        float s = 0.f;
        #pragma unroll
        for (int p = 0; p < PP; ++p) s += Pw[p * EE * EE + t];
        Pm[t] = s * 0.25f;
    }
    __syncthreads();

    // ---- Phase A: router logit for (row, e); each lane dots 192 elems ----
    const f32x4* x4 = (const f32x4*)(x + (size_t)row * DD);
    const f32x4* w4 = (const f32x4*)(W + (size_t)e * DD);
    f32x4 acc = {0.f, 0.f, 0.f, 0.f};
    #pragma unroll 6
    for (int i = 0; i < 48; ++i) {
        const int k4 = seg + 4 * i;
        f32x4 a = x4[k4], b = w4[k4];
        acc.x = fmaf(a.x, b.x, acc.x);
        acc.y = fmaf(a.y, b.y, acc.y);
        acc.z = fmaf(a.z, b.z, acc.z);
        acc.w = fmaf(a.w, b.w, acc.w);
    }
    float part = (acc.x + acc.y) + (acc.z + acc.w);
    part += __shfl_xor(part, 16, 64);
    part += __shfl_xor(part, 32, 64);
    const float logit = part + bias[e];

    // top-1 across 16 experts
    float v0 = logit; int i0 = e;
    #pragma unroll
    for (int m = 1; m < 16; m <<= 1) {
        float ov = __shfl_xor(v0, m, 16);
        int   oi = __shfl_xor(i0, m, 16);
        if (ov > v0 || (ov == v0 && oi < i0)) { v0 = ov; i0 = oi; }
    }
    // top-2
    float v1 = (e == i0) ? -INFINITY : logit; int i1 = e;
    #pragma unroll
    for (int m = 1; m < 16; m <<= 1) {
        float ov = __shfl_xor(v1, m, 16);
        int   oi = __shfl_xor(i1, m, 16);
        if (ov > v1 || (ov == v1 && oi < i1)) { v1 = ov; i1 = oi; }
    }

    // reference quirk: scattered==0.0 -> -inf before softmax
    const float z0 = (v0 == 0.f) ? -INFINITY : v0;
    const float z1 = (v1 == 0.f) ? -INFINITY : v1;
    const float mx = fmaxf(z0, z1);
    const float e0 = expf(z0 - mx), e1 = expf(z1 - mx);
    const float inv = 1.f / (e0 + e1);
    const float sm0 = e0 * inv, sm1 = e1 * inv;

    const float s = sm0 * Pm[i0 * EE + e] + sm1 * Pm[i1 * EE + e];
    if (seg == 0) sp_lds[w][e] = s;
    __syncthreads();

    // ---- Phase B: stream h (R3 winner pattern) with NT stores for y ----
    const int q = t & 3;   // which expert-quad this lane owns
    for (int r = 0; r < RPB; ++r) {
        const f32x4 s4 = ((const f32x4*)&sp_lds[r][0])[q];
        const size_t rw = (size_t)(blockIdx.x * RPB + r);
        const f32x4* h4 = (const f32x4*)(h + rw * DD * EE);
        float* yr = y + rw * DD;
        #pragma unroll
        for (int it = 0; it < 12; ++it) {
            const int u = it * 256 + t;       // wave reads 1KB contiguous/instr
            f32x4 a = h4[u];
            float p = a.x * s4.x + a.y * s4.y + a.z * s4.z + a.w * s4.w;
            p += __shfl_xor(p, 1, 64);        // quad reduce
            p += __shfl_xor(p, 2, 64);
            if (q == 0) __builtin_nontemporal_store(p, yr + (u >> 2));
        }
    }

    // ---- per-block partials, transposed layout [32][NBLK] (after stream issue) ----
    if (t < EE) {
        partials[(size_t)t * NBLK + blockIdx.x] =
            sp_lds[0][t] + sp_lds[1][t] + sp_lds[2][t] + sp_lds[3][t];
    } else if (t < 2 * EE) {
        const int c = t - EE;
        float hs = 0.f;
        #pragma unroll
        for (int r = 0; r < RPB; ++r) hs += (sp_lds[r][c] >= 1e-5f) ? 1.f : 0.f;
        partials[(size_t)t * NBLK + blockIdx.x] = hs;
    }
}

// ---- K2: 32 blocks; block b streams its contiguous 8 KB row of partials. ----
__global__ __launch_bounds__(256) void avg_reduce(
    const float* __restrict__ partials,   // [32][NBLK]
    float* __restrict__ avgs)             // [32]
{
    __shared__ float red[4];
    const int t = threadIdx.x;
    const int b = blockIdx.x;
    const float* rowp = partials + (size_t)b * NBLK;

    float s = 0.f;
    #pragma unroll
    for (int k = 0; k < NBLK / 256; ++k)   // 8 coalesced passes
        s += rowp[t + k * 256];
    // wave reduce
    #pragma unroll
    for (int off = 32; off >= 1; off >>= 1)
        s += __shfl_xor(s, off, 64);
    if ((t & 63) == 0) red[t >> 6] = s;
    __syncthreads();
    if (t == 0)
        avgs[b] = (red[0] + red[1] + red[2] + red[3]) * (1.0f / (float)BB);
}

extern "C" void kernel_launch(void* const* d_in, const int* in_sizes, int n_in,
                              void* d_out, int out_size, void* d_ws, size_t ws_size,
                              hipStream_t stream) {
    const float* h    = (const float*)d_in[0];   // [8192, 768, 16]
    const float* x    = (const float*)d_in[1];   // [8192, 768]
    const float* W    = (const float*)d_in[2];   // [16, 768]
    const float* bias = (const float*)d_in[3];   // [16]
    const float* Pw   = (const float*)d_in[4];   // [4, 16, 16]

    float* y        = (float*)d_out;             // [8192, 768]
    float* avgs     = y + (size_t)BB * DD;       // soft[16] ++ hard[16]
    float* partials = (float*)d_ws;              // [32][2048] = 256 KB

    moe_fused<<<NBLK, 256, 0, stream>>>(h, x, W, bias, Pw, y, partials);
    avg_reduce<<<32, 256, 0, stream>>>(partials, avgs);
}